// Round 10
// baseline (113.868 us; speedup 1.0000x reference)
//
#include <hip/hip_runtime.h>
#include <hip/hip_fp16.h>

// MaddnessMatmul round 10: L1-gather encode with line-friendly lane layout.
//   out[m][n] = sum_c luts[c][enc(n,c)][m],  luts[c][k][m] = dot(B[m], P[c][k]).
//
// History: R8 (lane=row global gather) = 64 lines/instr -> TA-serialized, 60us.
// R9 (bpermute) = 4 crossbar ops per useful dword -> DS-pipe ~20us. R4-R7
// (LDS staging) = stage+gather+threshold DS + barrier convoys ~ same. All
// land 26-31us vs 11-13us HBM floor because the transpose rides the DS pipe.
// R10 rides the TA/L1 pipe instead:
//  - lane = (r = lane>>4 in 0..3, c = lane&15). Gather instr for level l:
//    addr = A[(row0+4p+r)*64 + sd[c][l]] -> touches 4 rows x <=4 lines =
//    <=16 distinct 64B lines (~16cyc TA), all 64 results useful. Per CU:
//    TA ~8.5us < HBM ~11us; rows live in L1 (1KB/pass).
//  - thresholds in 15 VGPRs/lane (c lane-constant): compare tree pure VALU.
//  - codes round-trip wave-private LDS region (lgkmcnt fence, no barrier).
//  - accum: 4x b128 code read, f16 LUT stride-24, even/odd packed-f16 sums,
//    f32 combine (absmax ~1.0 << 3.6 in prior rounds).
//  - LDS 12288+20480 = 32768B exactly -> 5 blocks/CU = 20 waves/CU.

#define NROWS 262144
#define LSTR  24          // halfs per LUT entry (48B)
#define CSTRD 20          // dwords per row in codes_s (80B, 16B-aligned)
#define TPB   256
#define NBLK  1024        // 1024 * 256 rows = 262144

typedef __attribute__((ext_vector_type(8))) _Float16 half8;
typedef __attribute__((ext_vector_type(4))) unsigned int u32x4;

#define WAVE_LDS_FENCE() asm volatile("s_waitcnt lgkmcnt(0)" ::: "memory")

__global__ __launch_bounds__(256) void lut_build(
    const float* __restrict__ B,      // [16][64]
    const float* __restrict__ P,      // [16][16][64]
    _Float16* __restrict__ lutw)      // [16][16][16] = c,k,m
{
    int o = blockIdx.x * 256 + threadIdx.x;   // o = c*256 + k*16 + m
    int m  = o & 15;
    int ck = o >> 4;
    const float4* Bp = (const float4*)(B + m * 64);
    const float4* Pp = (const float4*)(P + ck * 64);
    float dot = 0.f;
    #pragma unroll
    for (int q = 0; q < 16; ++q) {
        float4 b = Bp[q], p = Pp[q];
        dot += b.x * p.x + b.y * p.y + b.z * p.z + b.w * p.w;
    }
    lutw[o] = (_Float16)dot;
}

__global__ __launch_bounds__(TPB) void maddness_fused(
    const float* __restrict__ A,      // [N][64]
    const int*   __restrict__ sd,     // [16][4]
    const float* __restrict__ sv,     // [16][4][8]
    const _Float16* __restrict__ lutw,// [256][16] f16
    float* __restrict__ out)          // [16][N]
{
    __shared__ __align__(16) _Float16 lut_s[256 * LSTR];  // 12,288 B
    __shared__ __align__(16) int codes_s[256 * CSTRD];    // 20,480 B

    const int t    = threadIdx.x;
    const int lane = t & 63;
    const int w    = t >> 6;
    const int r    = lane >> 4;    // row-within-quad this lane encodes
    const int c    = lane & 15;    // codebook this lane owns

    // ---- stage f16 LUT (one 32B entry/thread, stride 24 halfs) ----
    {
        const u32x4* src = (const u32x4*)(lutw + t * 16);
        u32x4 q0 = src[0], q1 = src[1];
        *(u32x4*)(lut_s + t * LSTR)     = q0;
        *(u32x4*)(lut_s + t * LSTR + 8) = q1;
    }

    // ---- per-lane constants: row-relative gather offsets + thresholds ----
    const int off0 = r * 64 + sd[c*4+0];
    const int off1 = r * 64 + sd[c*4+1];
    const int off2 = r * 64 + sd[c*4+2];
    const int off3 = r * 64 + sd[c*4+3];

    const float* svc = sv + c * 32;     // lane-varying small gather, once
    const float v0   = svc[0];
    const float v1a  = svc[8],  v1b = svc[9];
    const float v2_0 = svc[16], v2_1 = svc[17], v2_2 = svc[18], v2_3 = svc[19];
    const float v3_0 = svc[24], v3_1 = svc[25], v3_2 = svc[26], v3_3 = svc[27];
    const float v3_4 = svc[28], v3_5 = svc[29], v3_6 = svc[30], v3_7 = svc[31];

    __syncthreads();   // LUT visible block-wide (once; also drains init loads)

    const int wrow0 = blockIdx.x * TPB + w * 64;   // this wave's 64 rows

    #pragma unroll
    for (int p = 0; p < 16; ++p) {
        // 4 rows per pass; each gather instr touches <=16 distinct lines
        const float* Abase = A + (size_t)(wrow0 + 4 * p) * 64;
        float x0 = Abase[off0];
        float x1 = Abase[off1];
        float x2 = Abase[off2];
        float x3 = Abase[off3];

        // threshold tree: registers only
        int g = (x0 > v0) ? 1 : 0;
        float t1 = g ? v1b : v1a;
        g = (g << 1) | ((x1 > t1) ? 1 : 0);
        float ta = (g & 1) ? v2_1 : v2_0;
        float tb = (g & 1) ? v2_3 : v2_2;
        float t2 = (g & 2) ? tb : ta;
        g = (g << 1) | ((x2 > t2) ? 1 : 0);
        float u0 = (g & 1) ? v3_1 : v3_0;
        float u1 = (g & 1) ? v3_3 : v3_2;
        float u2 = (g & 1) ? v3_5 : v3_4;
        float u3 = (g & 1) ? v3_7 : v3_6;
        float w0 = (g & 2) ? u1 : u0;
        float w1 = (g & 2) ? u3 : u2;
        float t3 = (g & 4) ? w1 : w0;
        g = (g << 1) | ((x3 > t3) ? 1 : 0);

        // wave-private codes region: row (w*64 + 4p + r), slot c
        codes_s[(w*64 + 4*p + r) * CSTRD + c] = g;
    }

    WAVE_LDS_FENCE();   // own-wave ds_write -> ds_read ordering; no vmcnt drain

    // ---- accumulate: thread t owns block-local row t (within own wave) ----
    const int* crow = codes_s + (size_t)t * CSTRD;
    const int4 q0 = *(const int4*)(crow);
    const int4 q1 = *(const int4*)(crow + 4);
    const int4 q2 = *(const int4*)(crow + 8);
    const int4 q3 = *(const int4*)(crow + 12);

    half8 aE0 = {0,0,0,0,0,0,0,0}, aE1 = {0,0,0,0,0,0,0,0};
    half8 aO0 = {0,0,0,0,0,0,0,0}, aO1 = {0,0,0,0,0,0,0,0};

#define ACC(cc, gg)                                                        \
    {                                                                      \
        const _Float16* lp = lut_s + ((cc) * 16 + (gg)) * LSTR;            \
        half8 l0 = *(const half8*)(lp);                                    \
        half8 l1 = *(const half8*)(lp + 8);                                \
        if ((cc) & 1) { aO0 += l0; aO1 += l1; }                            \
        else          { aE0 += l0; aE1 += l1; }                            \
    }
    ACC(0,  q0.x) ACC(1,  q0.y) ACC(2,  q0.z) ACC(3,  q0.w)
    ACC(4,  q1.x) ACC(5,  q1.y) ACC(6,  q1.z) ACC(7,  q1.w)
    ACC(8,  q2.x) ACC(9,  q2.y) ACC(10, q2.z) ACC(11, q2.w)
    ACC(12, q3.x) ACC(13, q3.y) ACC(14, q3.z) ACC(15, q3.w)
#undef ACC

    const int n = blockIdx.x * TPB + t;
    #pragma unroll
    for (int m = 0; m < 8; ++m) {
        out[(long)m       * NROWS + n] = (float)aE0[m] + (float)aO0[m];
        out[(long)(m + 8) * NROWS + n] = (float)aE1[m] + (float)aO1[m];
    }
}

extern "C" void kernel_launch(void* const* d_in, const int* in_sizes, int n_in,
                              void* d_out, int out_size, void* d_ws, size_t ws_size,
                              hipStream_t stream) {
    const float* A  = (const float*)d_in[0];
    const float* B  = (const float*)d_in[1];
    const float* P  = (const float*)d_in[2];
    const int*   sd = (const int*)d_in[3];
    const float* sv = (const float*)d_in[4];
    float* out = (float*)d_out;

    _Float16* lutw = (_Float16*)d_ws;   // 8 KB f16 LUT

    lut_build<<<dim3(16), dim3(256), 0, stream>>>(B, P, lutw);
    maddness_fused<<<dim3(NBLK), dim3(TPB), 0, stream>>>(A, sd, sv, lutw, out);
}